// Round 7
// baseline (21.585 us; speedup 1.0000x reference)
//
#include <hip/hip_runtime.h>
#include <hip/hip_fp16.h>
#include <math.h>

#define N_G   1024
#define IMG_H 256
#define IMG_W 256
#define G_EPS 1e-4f
#define LOG2E 1.4426950408889634f
#define TILE_HALF 3.5f         // pixel centers within 8x8 tile are <= 3.5 from center
#define CULL_INV_EPS 1.0e6f    // 1/eps, eps = 1e-6 contribution cutoff

// ws layout (floats):
//   gp[0    ..4095]  : float4 cull[1024]   (mx, my, hx+3.5, hy+3.5) sorted order
//   gp[4096 ..12287] : float  rec[1024][8]:
//     [0] mean_x [1] mean_y
//     [2] c2 = -0.5*d*invdet*LOG2E     (dx^2 coeff, log2 domain)
//     [3] c3 = +0.5*(b+c)*invdet*LOG2E (dx*dy coeff)
//     [4] c4 = -0.5*a*invdet*LOG2E     (dy^2 coeff)
//     [5] c5 = log2(premult)           (folded into exponent)
//     [6] r,g packed fp16x2  [7] b (fp32)
// ---------------------------------------------------------------------------
__global__ __launch_bounds__(256) void prep_sort_kernel(
    const float* __restrict__ means3D,
    const float* __restrict__ covs3d,
    const float* __restrict__ colors,
    const float* __restrict__ opacities,
    const float* __restrict__ Km,
    const float* __restrict__ Rm,
    const float* __restrict__ tv,
    float* __restrict__ gp)
{
    __shared__ alignas(16) float sd[N_G];
    __shared__ int pr[4][64];

    const int t = threadIdx.x;
    const int b = blockIdx.x;

    const float R20=Rm[6],R21=Rm[7],R22=Rm[8];
    const float t2=tv[2];

    // phase 1: all 1024 depths, 4 per thread
    #pragma unroll
    for (int k = 0; k < 4; ++k) {
        const int g = t + 256*k;
        const float m0 = means3D[g*3+0], m1 = means3D[g*3+1], m2 = means3D[g*3+2];
        sd[g] = fmaxf(R20*m0 + R21*m1 + R22*m2 + t2, 1.0f);
    }
    __syncthreads();

    // phase 2: partial stable ranks (thread t: gaussian li=t&63, quarter q=t>>6)
    const int li = t & 63;
    const int q  = t >> 6;
    const int i  = b*64 + li;
    const float di = sd[i];
    int rank = 0;
    const int j0 = q*256;
    for (int j = j0; j < j0 + 256; j += 4) {
        const float4 d4 = *(const float4*)&sd[j];
        rank += (d4.x < di) || (d4.x == di && (j+0) < i);
        rank += (d4.y < di) || (d4.y == di && (j+1) < i);
        rank += (d4.z < di) || (d4.z == di && (j+2) < i);
        rank += (d4.w < di) || (d4.w == di && (j+3) < i);
    }
    pr[q][li] = rank;
    __syncthreads();

    // phase 3: first 64 threads: full projection + record at sorted position
    if (t < 64) {
        const int gi = b*64 + t;
        const int r  = pr[0][t] + pr[1][t] + pr[2][t] + pr[3][t];

        const float m0 = means3D[gi*3+0], m1 = means3D[gi*3+1], m2 = means3D[gi*3+2];
        const float R00=Rm[0],R01=Rm[1],R02=Rm[2];
        const float R10=Rm[3],R11=Rm[4],R12=Rm[5];
        const float t0=tv[0],t1=tv[1];

        const float camx = R00*m0 + R01*m1 + R02*m2 + t0;
        const float camy = R10*m0 + R11*m1 + R12*m2 + t1;
        const float camz = R20*m0 + R21*m1 + R22*m2 + t2;
        const float depth = fmaxf(camz, 1.0f);

        const float K00=Km[0],K01=Km[1],K02=Km[2];
        const float K10=Km[3],K11=Km[4],K12=Km[5];
        const float K20=Km[6],K21=Km[7],K22=Km[8];

        const float u = K00*camx + K01*camy + K02*camz;
        const float v = K10*camx + K11*camy + K12*camz;
        const float z = K20*camx + K21*camy + K22*camz;

        const float mx = u / z;
        const float my = v / z;

        const float inv_z2 = 1.0f / (z*z);
        const float J00 = K00/z - u*inv_z2;
        const float J01 = K01/z - v*inv_z2;
        const float J02 = -u*inv_z2;
        const float J10 = K10/z - u*inv_z2;
        const float J11 = K11/z - v*inv_z2;
        const float J12 = -v*inv_z2;

        const float* S = covs3d + gi*9;
        const float S00=S[0],S01=S[1],S02=S[2];
        const float S10=S[3],S11=S[4],S12=S[5];
        const float S20=S[6],S21=S[7],S22=S[8];

        // M = R*S
        const float M00 = R00*S00 + R01*S10 + R02*S20;
        const float M01 = R00*S01 + R01*S11 + R02*S21;
        const float M02 = R00*S02 + R01*S12 + R02*S22;
        const float M10 = R10*S00 + R11*S10 + R12*S20;
        const float M11 = R10*S01 + R11*S11 + R12*S21;
        const float M12 = R10*S02 + R11*S12 + R12*S22;
        const float M20 = R20*S00 + R21*S10 + R22*S20;
        const float M21 = R20*S01 + R21*S11 + R22*S21;
        const float M22 = R20*S02 + R21*S12 + R22*S22;

        // C = M*R^T
        const float C00 = M00*R00 + M01*R01 + M02*R02;
        const float C01 = M00*R10 + M01*R11 + M02*R12;
        const float C02 = M00*R20 + M01*R21 + M02*R22;
        const float C10 = M10*R00 + M11*R01 + M12*R02;
        const float C11 = M10*R10 + M11*R11 + M12*R12;
        const float C12 = M10*R20 + M11*R21 + M12*R22;
        const float C20 = M20*R00 + M21*R01 + M22*R02;
        const float C21 = M20*R10 + M21*R11 + M22*R12;
        const float C22 = M20*R20 + M21*R21 + M22*R22;

        // JC = J*C (2x3)
        const float JC00 = J00*C00 + J01*C10 + J02*C20;
        const float JC01 = J00*C01 + J01*C11 + J02*C21;
        const float JC02 = J00*C02 + J01*C12 + J02*C22;
        const float JC10 = J10*C00 + J11*C10 + J12*C20;
        const float JC11 = J10*C01 + J11*C11 + J12*C21;
        const float JC12 = J10*C02 + J11*C12 + J12*C22;

        // V = JC*J^T + EPS*I
        const float a = JC00*J00 + JC01*J01 + JC02*J02 + G_EPS;
        const float bb= JC00*J10 + JC01*J11 + JC02*J12;
        const float c = JC10*J00 + JC11*J01 + JC12*J02;
        const float d = JC10*J10 + JC11*J11 + JC12*J12 + G_EPS;

        const float det = a*d - bb*c;
        const float inv_det = 1.0f / det;
        const bool valid = (depth > 1.0f) && (depth < 50.0f);
        const float normalizer = 0.15915494309189535f / sqrtf(det);
        const float premult = valid ? (opacities[gi] * normalizer) : 0.0f;

        // ln-domain conic Q = 0.5*invdet*[[d, -(b+c)/2],[-(b+c)/2, a]]
        // eps-level-set ellipse q(v)=L, L = ln(premult/eps).
        // AABB half-extents: hx = sqrt(L*Qyy/detQ), hy = sqrt(L*Qxx/detQ)
        const float Qxx  = 0.5f * inv_det * d;
        const float Qyy  = 0.5f * inv_det * a;
        const float detQ = 0.25f * inv_det * inv_det * (a*d - 0.25f*(bb+c)*(bb+c));
        float hx = -1.0f, hy = -1.0f;
        const float ratio = premult * CULL_INV_EPS;   // premult/eps
        if (ratio > 1.0f && detQ > 0.0f) {
            const float L = logf(ratio);
            const float s = L / detQ;
            hx = sqrtf(fmaxf(s * Qyy, 0.0f)) + TILE_HALF;
            hy = sqrtf(fmaxf(s * Qxx, 0.0f)) + TILE_HALF;
        }

        const float c5 = (premult > 0.0f) ? __log2f(premult) : -1e30f;

        ((float4*)gp)[r] = make_float4(mx, my, hx, hy);

        __half2 rg = __floats2half2_rn(colors[gi*3+0], colors[gi*3+1]);
        const float rgf = __uint_as_float(*reinterpret_cast<unsigned*>(&rg));

        float* o = gp + 4096 + r*8;
        *(float4*)(o + 0) = make_float4(mx, my,
                                        -0.5f * d * inv_det * LOG2E,
                                         0.5f * (bb + c) * inv_det * LOG2E);
        *(float4*)(o + 4) = make_float4(-0.5f * a * inv_det * LOG2E,
                                        c5,
                                        rgf,
                                        colors[gi*3+2]);
    }
}

// ---------------------------------------------------------------------------
// Kernel 2: per-tile cull+compact+composite.
// Grid 1024 blocks x 512 threads; block = one 8x8 tile via load-balancing
// permutation (blocks b, b+256, b+512, b+768 share a CU -> {far,near,near,far}).
// Compaction writes only u16 survivor INDICES to LDS (2KB). The composite loop
// reads records from GLOBAL (L2-resident, 32KB) at wave-UNIFORM addresses
// derived via readlane -> scalar/single-transaction loads, keeping the LDS
// pipe idle. 1-deep software prefetch hides L2 latency.
// ---------------------------------------------------------------------------
__global__ __launch_bounds__(512, 8) void render_kernel(
    const float* __restrict__ gp, float* __restrict__ out)
{
    __shared__ unsigned short sidx[N_G + 64];   // survivor indices + pad
    __shared__ float comb[7][4][64];
    __shared__ int wc[8];

    const int t    = threadIdx.x;
    const int lane = t & 63;
    const int w    = t >> 6;

    // block -> tile permutation for per-CU load balance
    const int bi = blockIdx.x;
    const int i  = bi & 255;
    const int qq = bi >> 8;
    const int x0 = i & 31;
    const int y0 = i >> 5;          // 0..7
    int tx, ty;
    switch (qq) {
        case 0:  tx = x0;             ty = y0;        break;  // rows 0-7   (far)
        case 1:  tx = (x0+16) & 31;   ty = y0 + 8;    break;  // rows 8-15  (near)
        case 2:  tx = (x0+16) & 31;   ty = 23 - y0;   break;  // rows 16-23 (near)
        default: tx = x0;             ty = 31 - y0;   break;  // rows 24-31 (far)
    }
    const float cx = (float)(tx << 3) + 3.5f;
    const float cy = (float)(ty << 3) + 3.5f;

    const float4* cull4 = (const float4*)gp;
    const float4* rec4  = (const float4*)(gp + 4096);  // rec[g] = rec4[2g], rec4[2g+1]

    if (t < 64) sidx[N_G + t] = 0;   // pad so chunk loads never read junk

    // --- cull (AABB) + order-preserving index compaction ---
    int total = 0;
    #pragma unroll
    for (int rnd = 0; rnd < 2; ++rnd) {
        const int g = rnd * 512 + t;
        const float4 cb = cull4[g];
        const bool keep = (fabsf(cb.x - cx) <= cb.z) & (fabsf(cb.y - cy) <= cb.w);
        const unsigned long long bm = __ballot(keep);
        if (lane == 0) wc[w] = __popcll(bm);
        __syncthreads();
        int baseW = 0, sumAll = 0;
        #pragma unroll
        for (int ii = 0; ii < 8; ++ii) {
            const int c = wc[ii];
            if (ii < w) baseW += c;
            sumAll += c;
        }
        if (keep) {
            const int pos = total + baseW + __popcll(bm & ((1ull << lane) - 1ull));
            sidx[pos] = (unsigned short)g;
        }
        total += sumAll;
        __syncthreads();
    }

    // --- composite survivors [k0,k1) for this segment ---
    const int p  = lane;        // pixel within 8x8 tile
    const int s  = w;           // segment 0..7
    const int px = (tx << 3) + (p & 7);
    const int py = (ty << 3) + (p >> 3);
    const float fpx = (float)px, fpy = (float)py;

    const int seg = (total + 7) >> 3;
    const int k0 = s * seg;
    const int k1 = (k0 + seg < total) ? (k0 + seg) : total;
    const int nvisit = k1 - k0;

    float T = 1.0f, cr = 0.0f, cg = 0.0f, cb2 = 0.0f;

    for (int base = 0; base < nvisit; base += 64) {
        const int cnt = (nvisit - base < 64) ? (nvisit - base) : 64;
        // lane-distributed indices for this chunk (one tiny LDS read / 64 visits)
        const int vidx = (int)sidx[k0 + base + lane];

        // prime the pipeline: record 0
        int id = __builtin_amdgcn_readlane(vidx, 0);
        float4 A = rec4[id*2+0];
        float4 B = rec4[id*2+1];

        for (int j = 0; j < cnt; ++j) {
            // prefetch j+1 (uniform address; redundant reload on last iter)
            const int jn = (j+1 < cnt) ? (j+1) : j;
            const int idn = __builtin_amdgcn_readlane(vidx, jn);
            const float4 An = rec4[idn*2+0];
            const float4 Bn = rec4[idn*2+1];

            const float dx = fpx - A.x;
            const float dy = fpy - A.y;
            const float t1 = fmaf(A.w, dy, A.z * dx);       // c2*dx + c3*dy
            const float h  = fmaf(B.x, dy*dy, B.y);         // c4*dy^2 + log2(pm)
            const float P2 = fmaf(dx, t1, h);
            const float alpha = __builtin_amdgcn_exp2f(P2); // = pm * gaussian
            const float wgt = T * alpha;
            unsigned rgbits = __float_as_uint(B.z);
            const float2 rg = __half22float2(*reinterpret_cast<__half2*>(&rgbits));
            cr  = fmaf(wgt, rg.x, cr);
            cg  = fmaf(wgt, rg.y, cg);
            cb2 = fmaf(wgt, B.w, cb2);
            T   = fmaf(-alpha, T, T);

            A = An; B = Bn;
        }
    }

    if (s > 0) {
        comb[s-1][0][p] = T;
        comb[s-1][1][p] = cr;
        comb[s-1][2][p] = cg;
        comb[s-1][3][p] = cb2;
    }
    __syncthreads();

    if (s == 0) {
        #pragma unroll
        for (int si = 0; si < 7; ++si) {
            cr  = fmaf(T, comb[si][1][p], cr);
            cg  = fmaf(T, comb[si][2][p], cg);
            cb2 = fmaf(T, comb[si][3][p], cb2);
            T *= comb[si][0][p];
        }
        const int pid = py * IMG_W + px;
        out[pid*3 + 0] = cr;
        out[pid*3 + 1] = cg;
        out[pid*3 + 2] = cb2;
    }
}

extern "C" void kernel_launch(void* const* d_in, const int* in_sizes, int n_in,
                              void* d_out, int out_size, void* d_ws, size_t ws_size,
                              hipStream_t stream) {
    const float* means3D   = (const float*)d_in[0];
    const float* covs3d    = (const float*)d_in[1];
    const float* colors    = (const float*)d_in[2];
    const float* opacities = (const float*)d_in[3];
    const float* Km        = (const float*)d_in[4];
    const float* Rm        = (const float*)d_in[5];
    const float* tv        = (const float*)d_in[6];

    float* gp = (float*)d_ws;   // 48 KB used

    hipLaunchKernelGGL(prep_sort_kernel, dim3(16), dim3(256), 0, stream,
                       means3D, covs3d, colors, opacities, Km, Rm, tv, gp);
    hipLaunchKernelGGL(render_kernel, dim3(1024), dim3(512), 0, stream,
                       gp, (float*)d_out);
}

// Round 8
// 20.251 us; speedup vs baseline: 1.0659x; 1.0659x over previous
//
#include <hip/hip_runtime.h>
#include <hip/hip_fp16.h>
#include <math.h>

#define N_G   1024
#define IMG_H 256
#define IMG_W 256
#define G_EPS 1e-4f
#define LOG2E 1.4426950408889634f
#define CULL_INV_EPS 1.0e6f    // 1/eps, eps = 1e-6 contribution cutoff

// ws layout (floats):
//   gp[0    ..4095]  : float4 cull[1024]   (mx, my, hx_raw, hy_raw) sorted order
//   gp[4096 ..12287] : float  rec[1024][8]:
//     [0] mean_x [1] mean_y
//     [2] c2 = -0.5*d*invdet*LOG2E     (dx^2 coeff, log2 domain)
//     [3] c3 = +0.5*(b+c)*invdet*LOG2E (dx*dy coeff)
//     [4] c4 = -0.5*a*invdet*LOG2E     (dy^2 coeff)
//     [5] c5 = log2(premult)           (folded into exponent)
//     [6] r,g packed fp16x2  [7] b (fp32)
// ---------------------------------------------------------------------------
__global__ __launch_bounds__(256) void prep_sort_kernel(
    const float* __restrict__ means3D,
    const float* __restrict__ covs3d,
    const float* __restrict__ colors,
    const float* __restrict__ opacities,
    const float* __restrict__ Km,
    const float* __restrict__ Rm,
    const float* __restrict__ tv,
    float* __restrict__ gp)
{
    __shared__ alignas(16) float sd[N_G];
    __shared__ int pr[4][64];

    const int t = threadIdx.x;
    const int b = blockIdx.x;

    const float R20=Rm[6],R21=Rm[7],R22=Rm[8];
    const float t2=tv[2];

    // phase 1: all 1024 depths, 4 per thread
    #pragma unroll
    for (int k = 0; k < 4; ++k) {
        const int g = t + 256*k;
        const float m0 = means3D[g*3+0], m1 = means3D[g*3+1], m2 = means3D[g*3+2];
        sd[g] = fmaxf(R20*m0 + R21*m1 + R22*m2 + t2, 1.0f);
    }
    __syncthreads();

    // phase 2: partial stable ranks (thread t: gaussian li=t&63, quarter q=t>>6)
    const int li = t & 63;
    const int q  = t >> 6;
    const int i  = b*64 + li;
    const float di = sd[i];
    int rank = 0;
    const int j0 = q*256;
    for (int j = j0; j < j0 + 256; j += 4) {
        const float4 d4 = *(const float4*)&sd[j];
        rank += (d4.x < di) || (d4.x == di && (j+0) < i);
        rank += (d4.y < di) || (d4.y == di && (j+1) < i);
        rank += (d4.z < di) || (d4.z == di && (j+2) < i);
        rank += (d4.w < di) || (d4.w == di && (j+3) < i);
    }
    pr[q][li] = rank;
    __syncthreads();

    // phase 3: first 64 threads: full projection + record at sorted position
    if (t < 64) {
        const int gi = b*64 + t;
        const int r  = pr[0][t] + pr[1][t] + pr[2][t] + pr[3][t];

        const float m0 = means3D[gi*3+0], m1 = means3D[gi*3+1], m2 = means3D[gi*3+2];
        const float R00=Rm[0],R01=Rm[1],R02=Rm[2];
        const float R10=Rm[3],R11=Rm[4],R12=Rm[5];
        const float t0=tv[0],t1=tv[1];

        const float camx = R00*m0 + R01*m1 + R02*m2 + t0;
        const float camy = R10*m0 + R11*m1 + R12*m2 + t1;
        const float camz = R20*m0 + R21*m1 + R22*m2 + t2;
        const float depth = fmaxf(camz, 1.0f);

        const float K00=Km[0],K01=Km[1],K02=Km[2];
        const float K10=Km[3],K11=Km[4],K12=Km[5];
        const float K20=Km[6],K21=Km[7],K22=Km[8];

        const float u = K00*camx + K01*camy + K02*camz;
        const float v = K10*camx + K11*camy + K12*camz;
        const float z = K20*camx + K21*camy + K22*camz;

        const float mx = u / z;
        const float my = v / z;

        const float inv_z2 = 1.0f / (z*z);
        const float J00 = K00/z - u*inv_z2;
        const float J01 = K01/z - v*inv_z2;
        const float J02 = -u*inv_z2;
        const float J10 = K10/z - u*inv_z2;
        const float J11 = K11/z - v*inv_z2;
        const float J12 = -v*inv_z2;

        const float* S = covs3d + gi*9;
        const float S00=S[0],S01=S[1],S02=S[2];
        const float S10=S[3],S11=S[4],S12=S[5];
        const float S20=S[6],S21=S[7],S22=S[8];

        // M = R*S
        const float M00 = R00*S00 + R01*S10 + R02*S20;
        const float M01 = R00*S01 + R01*S11 + R02*S21;
        const float M02 = R00*S02 + R01*S12 + R02*S22;
        const float M10 = R10*S00 + R11*S10 + R12*S20;
        const float M11 = R10*S01 + R11*S11 + R12*S21;
        const float M12 = R10*S02 + R11*S12 + R12*S22;
        const float M20 = R20*S00 + R21*S10 + R22*S20;
        const float M21 = R20*S01 + R21*S11 + R22*S21;
        const float M22 = R20*S02 + R21*S12 + R22*S22;

        // C = M*R^T
        const float C00 = M00*R00 + M01*R01 + M02*R02;
        const float C01 = M00*R10 + M01*R11 + M02*R12;
        const float C02 = M00*R20 + M01*R21 + M02*R22;
        const float C10 = M10*R00 + M11*R01 + M12*R02;
        const float C11 = M10*R10 + M11*R11 + M12*R12;
        const float C12 = M10*R20 + M11*R21 + M12*R22;
        const float C20 = M20*R00 + M21*R01 + M22*R02;
        const float C21 = M20*R10 + M21*R11 + M22*R12;
        const float C22 = M20*R20 + M21*R21 + M22*R22;

        // JC = J*C (2x3)
        const float JC00 = J00*C00 + J01*C10 + J02*C20;
        const float JC01 = J00*C01 + J01*C11 + J02*C21;
        const float JC02 = J00*C02 + J01*C12 + J02*C22;
        const float JC10 = J10*C00 + J11*C10 + J12*C20;
        const float JC11 = J10*C01 + J11*C11 + J12*C21;
        const float JC12 = J10*C02 + J11*C12 + J12*C22;

        // V = JC*J^T + EPS*I
        const float a = JC00*J00 + JC01*J01 + JC02*J02 + G_EPS;
        const float bb= JC00*J10 + JC01*J11 + JC02*J12;
        const float c = JC10*J00 + JC11*J01 + JC12*J02;
        const float d = JC10*J10 + JC11*J11 + JC12*J12 + G_EPS;

        const float det = a*d - bb*c;
        const float inv_det = 1.0f / det;
        const bool valid = (depth > 1.0f) && (depth < 50.0f);
        const float normalizer = 0.15915494309189535f / sqrtf(det);
        const float premult = valid ? (opacities[gi] * normalizer) : 0.0f;

        // ln-domain conic Q = 0.5*invdet*[[d, -(b+c)/2],[-(b+c)/2, a]]
        // eps-level-set ellipse q(v)=L, L = ln(premult/eps).
        // AABB half-extents: hx = sqrt(L*Qyy/detQ), hy = sqrt(L*Qxx/detQ)
        const float Qxx  = 0.5f * inv_det * d;
        const float Qyy  = 0.5f * inv_det * a;
        const float detQ = 0.25f * inv_det * inv_det * (a*d - 0.25f*(bb+c)*(bb+c));
        float hx = -1.0e9f, hy = -1.0e9f;   // sentinel: never kept
        const float ratio = premult * CULL_INV_EPS;   // premult/eps
        if (ratio > 1.0f && detQ > 0.0f) {
            const float L = logf(ratio);
            const float s = L / detQ;
            hx = sqrtf(fmaxf(s * Qyy, 0.0f));
            hy = sqrtf(fmaxf(s * Qxx, 0.0f));
        }

        const float c5 = (premult > 0.0f) ? __log2f(premult) : -1e30f;

        ((float4*)gp)[r] = make_float4(mx, my, hx, hy);

        __half2 rg = __floats2half2_rn(colors[gi*3+0], colors[gi*3+1]);
        const float rgf = __uint_as_float(*reinterpret_cast<unsigned*>(&rg));

        float* o = gp + 4096 + r*8;
        *(float4*)(o + 0) = make_float4(mx, my,
                                        -0.5f * d * inv_det * LOG2E,
                                         0.5f * (bb + c) * inv_det * LOG2E);
        *(float4*)(o + 4) = make_float4(-0.5f * a * inv_det * LOG2E,
                                        c5,
                                        rgf,
                                        colors[gi*3+2]);
    }
}

// ---------------------------------------------------------------------------
// Kernel 2: per-tile cull+compact+composite, 2 pixels per lane.
// Grid 512 blocks x 512 threads. Block = one 16x8 pixel tile (load-balance
// permutation pairs row y with y+16 on the same CU across dispatch rounds).
// Thread t: lane covers pixels (lx, ly) and (lx, ly+4) of the tile; segment
// s = t>>6 (0..7) composites survivors [s*seg, (s+1)*seg); segments combined
// with C = C0 + T0*(C1 + T1*(...)).
// Record broadcast (2 x ds_read_b128) now serves 128 pixel-visits per wave.
// ---------------------------------------------------------------------------
__global__ __launch_bounds__(512, 4) void render_kernel(
    const float* __restrict__ gp, float* __restrict__ out)
{
    __shared__ alignas(16) float sgrec[N_G * 8];   // 32 KB worst case
    __shared__ float comb[7][4][128];              // 14 KB
    __shared__ int wc0[8], wc1[8];

    const int t    = threadIdx.x;
    const int lane = t & 63;
    const int w    = t >> 6;

    // block -> tile permutation: 512 tiles (16 x-tiles, 32 y-tiles).
    // blocks b and b+256 land on the same CU (round-robin); pair rows y,y+16.
    const int bi = blockIdx.x;
    const int i  = bi & 255;
    const int qq = bi >> 8;         // 0 or 1
    const int x0 = i & 15;
    const int y0 = i >> 4;          // 0..15
    const int tx = qq ? ((x0 + 8) & 15) : x0;
    const int ty = qq ? (y0 + 16) : y0;

    const float cx = (float)(tx << 4) + 7.5f;
    const float cy = (float)(ty << 3) + 3.5f;

    const float4* cull4 = (const float4*)gp;
    const float*  rec   = gp + 4096;

    // --- cull (AABB, anisotropic margins) + order-preserving compaction ---
    const int ga = t, gb = 512 + t;
    const float4 ca = cull4[ga];
    const float4 cbq = cull4[gb];
    const bool keepA = (fabsf(ca.x  - cx) <= ca.z  + 7.5f) &
                       (fabsf(ca.y  - cy) <= ca.w  + 3.5f);
    const bool keepB = (fabsf(cbq.x - cx) <= cbq.z + 7.5f) &
                       (fabsf(cbq.y - cy) <= cbq.w + 3.5f);
    const unsigned long long bmA = __ballot(keepA);
    const unsigned long long bmB = __ballot(keepB);
    if (lane == 0) { wc0[w] = __popcll(bmA); wc1[w] = __popcll(bmB); }
    __syncthreads();
    int baseA = 0, baseB = 0, sumA = 0, total = 0;
    #pragma unroll
    for (int ii = 0; ii < 8; ++ii) {
        const int c0 = wc0[ii], c1 = wc1[ii];
        if (ii < w) { baseA += c0; baseB += c1; }
        sumA  += c0;
        total += c0 + c1;
    }
    if (keepA) {
        const int pos = baseA + __popcll(bmA & ((1ull << lane) - 1ull));
        const float4* s4 = (const float4*)(rec + ga*8);
        float4* dst = (float4*)&sgrec[pos * 8];
        dst[0] = s4[0]; dst[1] = s4[1];
    }
    if (keepB) {
        const int pos = sumA + baseB + __popcll(bmB & ((1ull << lane) - 1ull));
        const float4* s4 = (const float4*)(rec + gb*8);
        float4* dst = (float4*)&sgrec[pos * 8];
        dst[0] = s4[0]; dst[1] = s4[1];
    }
    __syncthreads();

    // --- composite: 2 pixels per lane, segments over depth ---
    const int lx = lane & 15;
    const int ly = lane >> 4;       // 0..3
    const int s  = w;               // segment 0..7
    const int px  = (tx << 4) + lx;
    const int py0 = (ty << 3) + ly; // second pixel at py0+4
    const float fpx = (float)px, fpy0 = (float)py0;

    const int seg = (total + 7) >> 3;
    const int k0 = s * seg;
    const int k1 = (k0 + seg < total) ? (k0 + seg) : total;

    float T0 = 1.0f, cr0 = 0.0f, cg0 = 0.0f, cb0 = 0.0f;
    float T1 = 1.0f, cr1 = 0.0f, cg1 = 0.0f, cb1 = 0.0f;

    for (int k = k0; k < k1; ++k) {
        const float4* g4 = (const float4*)&sgrec[k * 8];
        const float4 A = g4[0];  // mx,my,c2,c3
        const float4 B = g4[1];  // c4,c5,rg16,b

        const float dx   = fpx - A.x;           // shared between both pixels
        const float c2dx = A.z * dx;
        const float dy0  = fpy0 - A.y;
        const float dy1  = dy0 + 4.0f;

        const float t10 = fmaf(A.w, dy0, c2dx);
        const float t11 = fmaf(A.w, dy1, c2dx);
        const float h0  = fmaf(B.x * dy0, dy0, B.y);
        const float h1  = fmaf(B.x * dy1, dy1, B.y);
        const float P0  = fmaf(dx, t10, h0);
        const float P1  = fmaf(dx, t11, h1);
        const float al0 = __builtin_amdgcn_exp2f(P0);
        const float al1 = __builtin_amdgcn_exp2f(P1);

        unsigned rgbits = __float_as_uint(B.z);
        const float2 rg = __half22float2(*reinterpret_cast<__half2*>(&rgbits));

        const float w0 = T0 * al0;
        const float w1 = T1 * al1;
        cr0 = fmaf(w0, rg.x, cr0);  cr1 = fmaf(w1, rg.x, cr1);
        cg0 = fmaf(w0, rg.y, cg0);  cg1 = fmaf(w1, rg.y, cg1);
        cb0 = fmaf(w0, B.w, cb0);   cb1 = fmaf(w1, B.w, cb1);
        T0  = fmaf(-al0, T0, T0);   T1  = fmaf(-al1, T1, T1);
    }

    if (s > 0) {
        comb[s-1][0][lane]    = T0;
        comb[s-1][1][lane]    = cr0;
        comb[s-1][2][lane]    = cg0;
        comb[s-1][3][lane]    = cb0;
        comb[s-1][0][lane+64] = T1;
        comb[s-1][1][lane+64] = cr1;
        comb[s-1][2][lane+64] = cg1;
        comb[s-1][3][lane+64] = cb1;
    }
    __syncthreads();

    if (s == 0) {
        #pragma unroll
        for (int si = 0; si < 7; ++si) {
            cr0 = fmaf(T0, comb[si][1][lane], cr0);
            cg0 = fmaf(T0, comb[si][2][lane], cg0);
            cb0 = fmaf(T0, comb[si][3][lane], cb0);
            T0 *= comb[si][0][lane];
            cr1 = fmaf(T1, comb[si][1][lane+64], cr1);
            cg1 = fmaf(T1, comb[si][2][lane+64], cg1);
            cb1 = fmaf(T1, comb[si][3][lane+64], cb1);
            T1 *= comb[si][0][lane+64];
        }
        const int pid0 = py0 * IMG_W + px;
        const int pid1 = (py0 + 4) * IMG_W + px;
        out[pid0*3 + 0] = cr0;
        out[pid0*3 + 1] = cg0;
        out[pid0*3 + 2] = cb0;
        out[pid1*3 + 0] = cr1;
        out[pid1*3 + 1] = cg1;
        out[pid1*3 + 2] = cb1;
    }
}

extern "C" void kernel_launch(void* const* d_in, const int* in_sizes, int n_in,
                              void* d_out, int out_size, void* d_ws, size_t ws_size,
                              hipStream_t stream) {
    const float* means3D   = (const float*)d_in[0];
    const float* covs3d    = (const float*)d_in[1];
    const float* colors    = (const float*)d_in[2];
    const float* opacities = (const float*)d_in[3];
    const float* Km        = (const float*)d_in[4];
    const float* Rm        = (const float*)d_in[5];
    const float* tv        = (const float*)d_in[6];

    float* gp = (float*)d_ws;   // 48 KB used

    hipLaunchKernelGGL(prep_sort_kernel, dim3(16), dim3(256), 0, stream,
                       means3D, covs3d, colors, opacities, Km, Rm, tv, gp);
    hipLaunchKernelGGL(render_kernel, dim3(512), dim3(512), 0, stream,
                       gp, (float*)d_out);
}

// Round 9
// 19.789 us; speedup vs baseline: 1.0907x; 1.0233x over previous
//
#include <hip/hip_runtime.h>
#include <hip/hip_fp16.h>
#include <math.h>

#define N_G   1024
#define IMG_H 256
#define IMG_W 256
#define G_EPS 1e-4f
#define LOG2E 1.4426950408889634f
#define CULL_INV_EPS 5.0e5f    // 1/eps, eps = 2e-6 contribution cutoff

// ws layout (floats):
//   gp[0   ..4095 ] : float4 cullA[1024]  (mx, my, alpha, beta)   sorted order
//   gp[4096..8191 ] : float4 cullB[1024]  (gamma, L, e1, e2)
//                     q(d) = a*dx^2 + b*dxdy + g*dy^2 (ln-domain conic, PSD)
//                     keep tile iff min_{d in rect} q(d) <= L = ln(pm/eps)
//                     e1 = -beta/(2*gamma), e2 = -beta/(2*alpha)
//   gp[8192..16383] : float  rec[1024][8]:
//     [0] mean_x [1] mean_y
//     [2] c2 = -alpha*LOG2E  [3] c3 = -beta*LOG2E  [4] c4 = -gamma*LOG2E
//     [5] c5 = log2(premult) [6] r,g packed fp16x2 [7] b (fp32)
// ---------------------------------------------------------------------------
__global__ __launch_bounds__(256) void prep_sort_kernel(
    const float* __restrict__ means3D,
    const float* __restrict__ covs3d,
    const float* __restrict__ colors,
    const float* __restrict__ opacities,
    const float* __restrict__ Km,
    const float* __restrict__ Rm,
    const float* __restrict__ tv,
    float* __restrict__ gp)
{
    __shared__ alignas(16) float sd[N_G];
    __shared__ int pr[4][64];

    const int t = threadIdx.x;
    const int b = blockIdx.x;

    const float R20=Rm[6],R21=Rm[7],R22=Rm[8];
    const float t2=tv[2];

    // phase 1: all 1024 depths, 4 per thread
    #pragma unroll
    for (int k = 0; k < 4; ++k) {
        const int g = t + 256*k;
        const float m0 = means3D[g*3+0], m1 = means3D[g*3+1], m2 = means3D[g*3+2];
        sd[g] = fmaxf(R20*m0 + R21*m1 + R22*m2 + t2, 1.0f);
    }
    __syncthreads();

    // phase 2: partial stable ranks (thread t: gaussian li=t&63, quarter q=t>>6)
    const int li = t & 63;
    const int q  = t >> 6;
    const int i  = b*64 + li;
    const float di = sd[i];
    int rank = 0;
    const int j0 = q*256;
    for (int j = j0; j < j0 + 256; j += 4) {
        const float4 d4 = *(const float4*)&sd[j];
        rank += (d4.x < di) || (d4.x == di && (j+0) < i);
        rank += (d4.y < di) || (d4.y == di && (j+1) < i);
        rank += (d4.z < di) || (d4.z == di && (j+2) < i);
        rank += (d4.w < di) || (d4.w == di && (j+3) < i);
    }
    pr[q][li] = rank;
    __syncthreads();

    // phase 3: first 64 threads: full projection + record at sorted position
    if (t < 64) {
        const int gi = b*64 + t;
        const int r  = pr[0][t] + pr[1][t] + pr[2][t] + pr[3][t];

        const float m0 = means3D[gi*3+0], m1 = means3D[gi*3+1], m2 = means3D[gi*3+2];
        const float R00=Rm[0],R01=Rm[1],R02=Rm[2];
        const float R10=Rm[3],R11=Rm[4],R12=Rm[5];
        const float t0=tv[0],t1=tv[1];

        const float camx = R00*m0 + R01*m1 + R02*m2 + t0;
        const float camy = R10*m0 + R11*m1 + R12*m2 + t1;
        const float camz = R20*m0 + R21*m1 + R22*m2 + t2;
        const float depth = fmaxf(camz, 1.0f);

        const float K00=Km[0],K01=Km[1],K02=Km[2];
        const float K10=Km[3],K11=Km[4],K12=Km[5];
        const float K20=Km[6],K21=Km[7],K22=Km[8];

        const float u = K00*camx + K01*camy + K02*camz;
        const float v = K10*camx + K11*camy + K12*camz;
        const float z = K20*camx + K21*camy + K22*camz;

        const float mx = u / z;
        const float my = v / z;

        const float inv_z2 = 1.0f / (z*z);
        const float J00 = K00/z - u*inv_z2;
        const float J01 = K01/z - v*inv_z2;
        const float J02 = -u*inv_z2;
        const float J10 = K10/z - u*inv_z2;
        const float J11 = K11/z - v*inv_z2;
        const float J12 = -v*inv_z2;

        const float* S = covs3d + gi*9;
        const float S00=S[0],S01=S[1],S02=S[2];
        const float S10=S[3],S11=S[4],S12=S[5];
        const float S20=S[6],S21=S[7],S22=S[8];

        // M = R*S
        const float M00 = R00*S00 + R01*S10 + R02*S20;
        const float M01 = R00*S01 + R01*S11 + R02*S21;
        const float M02 = R00*S02 + R01*S12 + R02*S22;
        const float M10 = R10*S00 + R11*S10 + R12*S20;
        const float M11 = R10*S01 + R11*S11 + R12*S21;
        const float M12 = R10*S02 + R11*S12 + R12*S22;
        const float M20 = R20*S00 + R21*S10 + R22*S20;
        const float M21 = R20*S01 + R21*S11 + R22*S21;
        const float M22 = R20*S02 + R21*S12 + R22*S22;

        // C = M*R^T
        const float C00 = M00*R00 + M01*R01 + M02*R02;
        const float C01 = M00*R10 + M01*R11 + M02*R12;
        const float C02 = M00*R20 + M01*R21 + M02*R22;
        const float C10 = M10*R00 + M11*R01 + M12*R02;
        const float C11 = M10*R10 + M11*R11 + M12*R12;
        const float C12 = M10*R20 + M11*R21 + M12*R22;
        const float C20 = M20*R00 + M21*R01 + M22*R02;
        const float C21 = M20*R10 + M21*R11 + M22*R12;
        const float C22 = M20*R20 + M21*R21 + M22*R22;

        // JC = J*C (2x3)
        const float JC00 = J00*C00 + J01*C10 + J02*C20;
        const float JC01 = J00*C01 + J01*C11 + J02*C21;
        const float JC02 = J00*C02 + J01*C12 + J02*C22;
        const float JC10 = J10*C00 + J11*C10 + J12*C20;
        const float JC11 = J10*C01 + J11*C11 + J12*C21;
        const float JC12 = J10*C02 + J11*C12 + J12*C22;

        // V = JC*J^T + EPS*I
        const float a = JC00*J00 + JC01*J01 + JC02*J02 + G_EPS;
        const float bb= JC00*J10 + JC01*J11 + JC02*J12;
        const float c = JC10*J00 + JC11*J01 + JC12*J02;
        const float d = JC10*J10 + JC11*J11 + JC12*J12 + G_EPS;

        const float det = a*d - bb*c;
        const float inv_det = 1.0f / det;
        const bool valid = (depth > 1.0f) && (depth < 50.0f);
        const float normalizer = 0.15915494309189535f / sqrtf(det);
        const float premult = valid ? (opacities[gi] * normalizer) : 0.0f;

        // ln-domain conic: q(d) = alpha*dx^2 + beta*dx*dy + gamma*dy^2
        const float alpha = 0.5f * d * inv_det;
        const float beta  = -0.5f * (bb + c) * inv_det;
        const float gamma = 0.5f * a * inv_det;

        const float ratio = premult * CULL_INV_EPS;   // premult/eps
        const float L  = (ratio > 1.0f) ? logf(ratio) : -1.0f;
        const float e1 = -beta / (2.0f * gamma);
        const float e2 = -beta / (2.0f * alpha);

        const float c5 = (premult > 0.0f) ? __log2f(premult) : -1e30f;

        ((float4*)gp)[r]          = make_float4(mx, my, alpha, beta);
        ((float4*)(gp + 4096))[r] = make_float4(gamma, L, e1, e2);

        __half2 rg = __floats2half2_rn(colors[gi*3+0], colors[gi*3+1]);
        const float rgf = __uint_as_float(*reinterpret_cast<unsigned*>(&rg));

        float* o = gp + 8192 + r*8;
        *(float4*)(o + 0) = make_float4(mx, my,
                                        -alpha * LOG2E,
                                        -beta  * LOG2E);
        *(float4*)(o + 4) = make_float4(-gamma * LOG2E,
                                        c5,
                                        rgf,
                                        colors[gi*3+2]);
    }
}

// ---------------------------------------------------------------------------
// Kernel 2: per-tile EXACT cull + compact + composite, 2 pixels per lane.
// Grid 512 blocks x 512 threads. Block = one 16x8 pixel tile (load-balance
// permutation pairs rows y,y+16 on the same CU across rounds).
// Exact cull: min over the tile's pixel-center rect of the ln-domain conic
// q(d) (convex quadratic over a box: center-in-box check + 4 edge minima,
// closed form) compared to L. Keeps gaussian iff some pixel could see >= eps.
// ---------------------------------------------------------------------------
__global__ __launch_bounds__(512, 4) void render_kernel(
    const float* __restrict__ gp, float* __restrict__ out)
{
    __shared__ alignas(16) float sgrec[N_G * 8];   // 32 KB worst case
    __shared__ float comb[7][4][128];              // 14 KB
    __shared__ int wc0[8], wc1[8];

    const int t    = threadIdx.x;
    const int lane = t & 63;
    const int w    = t >> 6;

    // block -> tile permutation: 512 tiles (16 x-tiles, 32 y-tiles).
    const int bi = blockIdx.x;
    const int i  = bi & 255;
    const int qq = bi >> 8;         // 0 or 1
    const int x0 = i & 15;
    const int y0 = i >> 4;          // 0..15
    const int tx = qq ? ((x0 + 8) & 15) : x0;
    const int ty = qq ? (y0 + 16) : y0;

    const float cx = (float)(tx << 4) + 7.5f;
    const float cy = (float)(ty << 3) + 3.5f;

    const float4* cullA = (const float4*)gp;
    const float4* cullB = (const float4*)(gp + 4096);
    const float*  rec   = gp + 8192;

    // exact ellipse-vs-rect test for gaussian g (rect: pixel centers of tile)
    auto keep_test = [&](int g) -> bool {
        const float4 A = cullA[g];   // mx,my,alpha,beta
        const float4 B = cullB[g];   // gamma,L,e1,e2
        const float bx0 = cx - 7.5f - A.x, bx1 = bx0 + 15.0f;
        const float by0 = cy - 3.5f - A.y, by1 = by0 + 7.0f;
        // edge x = bx0 / bx1: dy* = clamp(e1*bx, by0, by1)
        float dy = fminf(fmaxf(B.z * bx0, by0), by1);
        float qm = fmaf(B.x * dy, dy, bx0 * fmaf(A.w, dy, A.z * bx0));
        dy = fminf(fmaxf(B.z * bx1, by0), by1);
        qm = fminf(qm, fmaf(B.x * dy, dy, bx1 * fmaf(A.w, dy, A.z * bx1)));
        // edge y = by0 / by1: dx* = clamp(e2*by, bx0, bx1)
        float dxq = fminf(fmaxf(B.w * by0, bx0), bx1);
        qm = fminf(qm, fmaf(A.z * dxq, dxq, by0 * fmaf(A.w, dxq, B.x * by0)));
        dxq = fminf(fmaxf(B.w * by1, bx0), bx1);
        qm = fminf(qm, fmaf(A.z * dxq, dxq, by1 * fmaf(A.w, dxq, B.x * by1)));
        // center inside rect -> q=0
        if ((bx0 <= 0.0f) & (bx1 >= 0.0f) & (by0 <= 0.0f) & (by1 >= 0.0f))
            qm = 0.0f;
        return qm <= B.y;
    };

    // --- cull + order-preserving compaction + stage records to LDS ---
    const int ga = t, gb = 512 + t;
    const bool keepA = keep_test(ga);
    const bool keepB = keep_test(gb);
    const unsigned long long bmA = __ballot(keepA);
    const unsigned long long bmB = __ballot(keepB);
    if (lane == 0) { wc0[w] = __popcll(bmA); wc1[w] = __popcll(bmB); }
    __syncthreads();
    int baseA = 0, baseB = 0, sumA = 0, total = 0;
    #pragma unroll
    for (int ii = 0; ii < 8; ++ii) {
        const int c0 = wc0[ii], c1 = wc1[ii];
        if (ii < w) { baseA += c0; baseB += c1; }
        sumA  += c0;
        total += c0 + c1;
    }
    if (keepA) {
        const int pos = baseA + __popcll(bmA & ((1ull << lane) - 1ull));
        const float4* s4 = (const float4*)(rec + ga*8);
        float4* dst = (float4*)&sgrec[pos * 8];
        dst[0] = s4[0]; dst[1] = s4[1];
    }
    if (keepB) {
        const int pos = sumA + baseB + __popcll(bmB & ((1ull << lane) - 1ull));
        const float4* s4 = (const float4*)(rec + gb*8);
        float4* dst = (float4*)&sgrec[pos * 8];
        dst[0] = s4[0]; dst[1] = s4[1];
    }
    __syncthreads();

    // --- composite: 2 pixels per lane, segments over depth ---
    const int lx = lane & 15;
    const int ly = lane >> 4;       // 0..3
    const int s  = w;               // segment 0..7
    const int px  = (tx << 4) + lx;
    const int py0 = (ty << 3) + ly; // second pixel at py0+4
    const float fpx = (float)px, fpy0 = (float)py0;

    const int seg = (total + 7) >> 3;
    const int k0 = s * seg;
    const int k1 = (k0 + seg < total) ? (k0 + seg) : total;

    float T0 = 1.0f, cr0 = 0.0f, cg0 = 0.0f, cb0 = 0.0f;
    float T1 = 1.0f, cr1 = 0.0f, cg1 = 0.0f, cb1 = 0.0f;

    for (int k = k0; k < k1; ++k) {
        const float4* g4 = (const float4*)&sgrec[k * 8];
        const float4 A = g4[0];  // mx,my,c2,c3
        const float4 B = g4[1];  // c4,c5,rg16,b

        const float dx   = fpx - A.x;           // shared between both pixels
        const float c2dx = A.z * dx;
        const float dy0  = fpy0 - A.y;
        const float dy1  = dy0 + 4.0f;

        const float t10 = fmaf(A.w, dy0, c2dx);
        const float t11 = fmaf(A.w, dy1, c2dx);
        const float h0  = fmaf(B.x * dy0, dy0, B.y);
        const float h1  = fmaf(B.x * dy1, dy1, B.y);
        const float P0  = fmaf(dx, t10, h0);
        const float P1  = fmaf(dx, t11, h1);
        const float al0 = __builtin_amdgcn_exp2f(P0);
        const float al1 = __builtin_amdgcn_exp2f(P1);

        unsigned rgbits = __float_as_uint(B.z);
        const float2 rg = __half22float2(*reinterpret_cast<__half2*>(&rgbits));

        const float w0 = T0 * al0;
        const float w1 = T1 * al1;
        cr0 = fmaf(w0, rg.x, cr0);  cr1 = fmaf(w1, rg.x, cr1);
        cg0 = fmaf(w0, rg.y, cg0);  cg1 = fmaf(w1, rg.y, cg1);
        cb0 = fmaf(w0, B.w, cb0);   cb1 = fmaf(w1, B.w, cb1);
        T0  = fmaf(-al0, T0, T0);   T1  = fmaf(-al1, T1, T1);
    }

    if (s > 0) {
        comb[s-1][0][lane]    = T0;
        comb[s-1][1][lane]    = cr0;
        comb[s-1][2][lane]    = cg0;
        comb[s-1][3][lane]    = cb0;
        comb[s-1][0][lane+64] = T1;
        comb[s-1][1][lane+64] = cr1;
        comb[s-1][2][lane+64] = cg1;
        comb[s-1][3][lane+64] = cb1;
    }
    __syncthreads();

    if (s == 0) {
        #pragma unroll
        for (int si = 0; si < 7; ++si) {
            cr0 = fmaf(T0, comb[si][1][lane], cr0);
            cg0 = fmaf(T0, comb[si][2][lane], cg0);
            cb0 = fmaf(T0, comb[si][3][lane], cb0);
            T0 *= comb[si][0][lane];
            cr1 = fmaf(T1, comb[si][1][lane+64], cr1);
            cg1 = fmaf(T1, comb[si][2][lane+64], cg1);
            cb1 = fmaf(T1, comb[si][3][lane+64], cb1);
            T1 *= comb[si][0][lane+64];
        }
        const int pid0 = py0 * IMG_W + px;
        const int pid1 = (py0 + 4) * IMG_W + px;
        out[pid0*3 + 0] = cr0;
        out[pid0*3 + 1] = cg0;
        out[pid0*3 + 2] = cb0;
        out[pid1*3 + 0] = cr1;
        out[pid1*3 + 1] = cg1;
        out[pid1*3 + 2] = cb1;
    }
}

extern "C" void kernel_launch(void* const* d_in, const int* in_sizes, int n_in,
                              void* d_out, int out_size, void* d_ws, size_t ws_size,
                              hipStream_t stream) {
    const float* means3D   = (const float*)d_in[0];
    const float* covs3d    = (const float*)d_in[1];
    const float* colors    = (const float*)d_in[2];
    const float* opacities = (const float*)d_in[3];
    const float* Km        = (const float*)d_in[4];
    const float* Rm        = (const float*)d_in[5];
    const float* tv        = (const float*)d_in[6];

    float* gp = (float*)d_ws;   // 64 KB used

    hipLaunchKernelGGL(prep_sort_kernel, dim3(16), dim3(256), 0, stream,
                       means3D, covs3d, colors, opacities, Km, Rm, tv, gp);
    hipLaunchKernelGGL(render_kernel, dim3(512), dim3(512), 0, stream,
                       gp, (float*)d_out);
}